// Round 1
// 251.286 us; speedup vs baseline: 1.3063x; 1.3063x over previous
//
#include <hip/hip_runtime.h>
#include <math.h>
#include <float.h>
#include <limits.h>
#include <stdint.h>

namespace {

constexpr int B  = 2;
constexpr int CK = 64;
constexpr int N  = 12960;   // T*H*W = 8*30*54
constexpr int M  = 1620;    // H*W = 30*54
constexpr int CV = 384;
constexpr int K  = 20;      // topk (setup fixed)

// segmented fused top-k geometry
constexpr int SEGN  = 1024;                    // n covered per stage-1 block
constexpr int NSEG  = (N + SEGN - 1) / SEGN;   // 13 segments
constexpr int CAP   = 64;                      // candidate slots per (m, seg); mean ~24, +8 sigma safe
constexpr int SLOTS = NSEG * CAP;              // 832 slots per (b, m)
constexpr int JC    = (SLOTS + 255) / 256;     // 4 candidate slots per thread in merge

static_assert((CAP & (CAP - 1)) == 0, "CAP must be pow2 (slot>>6 indexing)");
static_assert(NSEG * SEGN >= N, "segments must cover N");

// monotone float->uint key (order-preserving) and inverse
__device__ __forceinline__ uint32_t f2k(float x) {
  uint32_t u = __float_as_uint(x);
  return u ^ ((u & 0x80000000u) ? 0xFFFFFFFFu : 0x80000000u);
}
__device__ __forceinline__ float k2f(uint32_t k) {
  uint32_t u = (k & 0x80000000u) ? (k ^ 0x80000000u) : ~k;
  return __uint_as_float(u);
}
__device__ __forceinline__ uint32_t umax2(uint32_t a, uint32_t b) { return a > b ? a : b; }
__device__ __forceinline__ uint32_t umin2(uint32_t a, uint32_t b) { return a < b ? a : b; }

// K0: mvT[b][n][c] = mv[b][c][n]  (so gather reads are contiguous in c)
__global__ __launch_bounds__(256) void transpose_kernel(const float* __restrict__ mv,
                                                        float* __restrict__ mvT) {
  __shared__ float tile[64][65];
  int b = blockIdx.z;
  int n0 = blockIdx.x * 64;
  int c0 = blockIdx.y * 64;
  int tx = threadIdx.x & 63, ty = threadIdx.x >> 6;
  for (int r = ty; r < 64; r += 4) {
    int c = c0 + r, n = n0 + tx;
    tile[r][tx] = (n < N) ? mv[((size_t)b * CV + c) * N + n] : 0.f;
  }
  __syncthreads();
  for (int r = ty; r < 64; r += 4) {
    int n = n0 + r, c = c0 + tx;
    if (n < N) mvT[((size_t)b * N + n) * CV + c] = tile[tx][r];
  }
}

// K5: out[b][c][m] = outT[b][m][c]
__global__ __launch_bounds__(256) void transpose_out_kernel(const float* __restrict__ outT,
                                                            float* __restrict__ out) {
  __shared__ float tile[64][65];
  int b = blockIdx.z;
  int m0 = blockIdx.x * 64;
  int c0 = blockIdx.y * 64;
  int tx = threadIdx.x & 63, ty = threadIdx.x >> 6;
  for (int r = ty; r < 64; r += 4) {
    int m = m0 + r;
    if (m < M) tile[r][tx] = outT[((size_t)b * M + m) * CV + c0 + tx];
  }
  __syncthreads();
  for (int r = ty; r < 64; r += 4) {
    int c = c0 + r, m = m0 + tx;
    if (m < M) out[((size_t)b * CV + c) * M + m] = tile[tx][r];
  }
}

// K1: a_sq[b,n] = sum_c mk[b,c,n]^2
__global__ __launch_bounds__(256) void asq_kernel(const float* __restrict__ mk,
                                                  float* __restrict__ asq) {
  int i = blockIdx.x * 256 + threadIdx.x;
  if (i >= B * N) return;
  int b = i / N, n = i - b * N;
  const float* p = mk + (size_t)b * CK * N + n;
  float s = 0.f;
#pragma unroll
  for (int c = 0; c < CK; ++c) {
    float v = p[(size_t)c * N];
    s += v * v;
  }
  asq[i] = s;
}

// K2 (fused): per block, compute a 16m x 1024n affinity tile in registers
// (bit-identical c-ascending FMA chain to the previous aff_kernel) and emit
// only candidates that can be in the global top-20.
// Safety filter per (m, seg): theta = 20th-largest of the 64 per-lane maxima.
// The 20 lanes achieving the top-20 lane-maxima each hold a value >= theta,
// so >= 20 values >= theta exist -> theta <= segment's 20th value ->
// {v >= theta} superset of the segment top-20 (ties at the global threshold
// included: a value below its segment's theta has >= 20 strictly greater
// values in that segment alone, hence cannot be the global boundary).
// Expected |{v >= theta}| ~ 64*ln(64/44) ~ 24; CAP=64 is ~+8 sigma.
__global__ __launch_bounds__(256) void fused_kernel(const float* __restrict__ mk,
                                                    const float* __restrict__ qk,
                                                    const float* __restrict__ asq,
                                                    uint32_t* __restrict__ cnt,
                                                    uint2* __restrict__ pairs) {
  const int b = blockIdx.z;
  const int seg = blockIdx.x;          // 0..NSEG-1
  const int mg0 = blockIdx.y * 16;     // m-group base
  const int t = threadIdx.x;
  const int l = t & 63, w = t >> 6;    // lane, wave; wave w owns m = mg0+4w..+3

  __shared__ float qs[CK][20];         // 16 m padded to 20 (80B rows, 16B aligned)
  __shared__ uint32_t scnt[16];        // per-m candidate counters (wave-local use)

  for (int i = t; i < CK * 16; i += 256) {
    int c = i >> 4, ml = i & 15;
    int m = mg0 + ml;
    qs[c][ml] = (m < M) ? qk[((size_t)b * CK + c) * M + m] : 0.f;
  }
  if (t < 16) scnt[t] = 0u;
  __syncthreads();

  const int nb = seg * SEGN + 4 * l;   // lane's first n; chunks at +256 strides
  bool vch[4];
#pragma unroll
  for (int ch = 0; ch < 4; ++ch) vch[ch] = (nb + ch * 256) < N;  // N%4==0 -> whole float4 valid

  const float* mkb = mk + (size_t)b * CK * N + nb;

  float4 acc[4][4];  // [mj][ch]
#pragma unroll
  for (int mj = 0; mj < 4; ++mj)
#pragma unroll
    for (int ch = 0; ch < 4; ++ch) acc[mj][ch] = make_float4(0.f, 0.f, 0.f, 0.f);

#pragma unroll 2
  for (int c = 0; c < CK; ++c) {
    float4 kv[4];
#pragma unroll
    for (int ch = 0; ch < 4; ++ch)
      kv[ch] = vch[ch] ? *reinterpret_cast<const float4*>(mkb + (size_t)c * N + ch * 256)
                       : make_float4(0.f, 0.f, 0.f, 0.f);
    const float4 qv = *reinterpret_cast<const float4*>(&qs[c][w * 4]);  // wave-uniform -> broadcast
    const float qm[4] = {qv.x, qv.y, qv.z, qv.w};
#pragma unroll
    for (int mj = 0; mj < 4; ++mj)
#pragma unroll
      for (int ch = 0; ch < 4; ++ch) {
        acc[mj][ch].x += kv[ch].x * qm[mj];
        acc[mj][ch].y += kv[ch].y * qm[mj];
        acc[mj][ch].z += kv[ch].z * qm[mj];
        acc[mj][ch].w += kv[ch].w * qm[mj];
      }
  }

  float4 sq[4];
#pragma unroll
  for (int ch = 0; ch < 4; ++ch)
    sq[ch] = vch[ch] ? *reinterpret_cast<const float4*>(asq + (size_t)b * N + nb + ch * 256)
                     : make_float4(0.f, 0.f, 0.f, 0.f);

  for (int mj = 0; mj < 4; ++mj) {
    const int m = mg0 + w * 4 + mj;
    if (m >= M) break;  // wave-uniform
    uint32_t key[16];
    uint32_t lmax = 0u;
#pragma unroll
    for (int ch = 0; ch < 4; ++ch) {
      const float vx = (2.f * acc[mj][ch].x - sq[ch].x) * 0.125f;
      const float vy = (2.f * acc[mj][ch].y - sq[ch].y) * 0.125f;
      const float vz = (2.f * acc[mj][ch].z - sq[ch].z) * 0.125f;
      const float vw = (2.f * acc[mj][ch].w - sq[ch].w) * 0.125f;
      key[ch * 4 + 0] = vch[ch] ? f2k(vx) : 0u;
      key[ch * 4 + 1] = vch[ch] ? f2k(vy) : 0u;
      key[ch * 4 + 2] = vch[ch] ? f2k(vz) : 0u;
      key[ch * 4 + 3] = vch[ch] ? f2k(vw) : 0u;
      lmax = umax2(lmax, umax2(umax2(key[ch * 4 + 0], key[ch * 4 + 1]),
                               umax2(key[ch * 4 + 2], key[ch * 4 + 3])));
    }
    // bitonic ascending sort of the 64 lane maxima; lane 44 = 20th largest
    uint32_t s = lmax;
#pragma unroll
    for (int kk = 2; kk <= 64; kk <<= 1) {
#pragma unroll
      for (int jj = kk >> 1; jj > 0; jj >>= 1) {
        uint32_t o = __shfl_xor(s, jj, 64);
        bool keepMin = (((l & kk) == 0) == ((l & jj) == 0));
        s = keepMin ? umin2(s, o) : umax2(s, o);
      }
    }
    const uint32_t theta = __shfl(s, 44, 64);
    const size_t base = ((size_t)(b * M + m) * NSEG + seg) * CAP;
#pragma unroll
    for (int r = 0; r < 16; ++r) {
      if (key[r] >= theta) {  // invalid keys are 0, theta > 0 always
        uint32_t slot = atomicAdd(&scnt[w * 4 + mj], 1u);
        if (slot < CAP)
          pairs[base + slot] = make_uint2(key[r], (uint32_t)(nb + (r >> 2) * 256 + (r & 3)));
      }
    }
  }
  // publish counts (own-wave LDS atomics are program-ordered before this read)
  if (l < 4) {
    const int m = mg0 + w * 4 + l;
    if (m < M) {
      uint32_t c0 = scnt[w * 4 + l];
      cnt[(size_t)(b * M + m) * NSEG + seg] = (c0 < CAP) ? c0 : (uint32_t)CAP;
    }
  }
}

// K3: merge candidates -> exact global top-20 (4-pass radix select, min-index
// tie-break identical to before) + softmax + fused gather into outT[b][m][c].
__global__ __launch_bounds__(256) void merge_topk_gather(const uint32_t* __restrict__ cnt,
                                                         const uint2* __restrict__ pairs,
                                                         const float* __restrict__ mvT,
                                                         float* __restrict__ outT) {
  const int m = blockIdx.x, b = blockIdx.y;
  const int t = threadIdx.x;

  __shared__ uint32_t segc[NSEG];
  constexpr int HP = 268;  // 1072B rows: 16B-aligned, non-pow2 bank offset
  __shared__ int hist[4][4][HP];
  __shared__ int s_digit, s_before;
  __shared__ int wn[K];
  __shared__ uint32_t wk[K];
  __shared__ float sw[K];
  __shared__ int gcnt, ecnt, s_last;
  __shared__ int ebuf[K];
  __shared__ int rmin4[4];

  if (t < NSEG) segc[t] = cnt[(size_t)(b * M + m) * NSEG + t];
  __syncthreads();

  const uint2* pb = pairs + (size_t)(b * M + m) * SLOTS;
  uint32_t k[JC];
  uint32_t nn[JC];
#pragma unroll
  for (int j = 0; j < JC; ++j) {
    int idx = t + (j << 8);
    bool valid = (idx < SLOTS) && ((uint32_t)(idx & (CAP - 1)) < segc[idx >> 6]);
    if (valid) {
      uint2 pr = pb[idx];
      k[j] = pr.x;
      nn[j] = pr.y;
    } else {
      k[j] = 0u;
      nn[j] = 0u;
    }
  }

  int before = 0;
  uint32_t pref = 0;
  const int w = t >> 6;
  const int rp = (t >> 4) & 3;
  int* myhist = &hist[w][rp][0];

  for (int p = 0; p < 4; ++p) {
    const int s = 24 - 8 * p;
    for (int i = t; i < 16 * HP; i += 256) ((int*)hist)[i] = 0;
    __syncthreads();
    const int shHi = (p == 0) ? 0 : (s + 8);
#pragma unroll
    for (int j = 0; j < JC; ++j) {
      uint32_t key = k[j];
      bool act = (p == 0) || ((key >> shHi) == pref);
      if (act) atomicAdd(&myhist[(key >> s) & 255], 1);
    }
    __syncthreads();
    if (t < 64) {
      int d = 4 * t;
      int4 g = make_int4(0, 0, 0, 0);
#pragma unroll
      for (int ww = 0; ww < 4; ++ww)
#pragma unroll
        for (int rr = 0; rr < 4; ++rr) {
          int4 h = *reinterpret_cast<int4*>(&hist[ww][rr][d]);
          g.x += h.x; g.y += h.y; g.z += h.z; g.w += h.w;
        }
      int sl = g.x + g.y + g.z + g.w;
      int sfx = sl;
#pragma unroll
      for (int off = 1; off < 64; off <<= 1) {
        int o = __shfl_down(sfx, off);
        sfx += (t + off < 64) ? o : 0;
      }
      int above = sfx - sl;
      int rem = K - before;
      if (above < rem && rem <= sfx) {  // boundary digit in my 4-digit group
        int cum = above, ds;
        if (cum + g.w >= rem) ds = 3;
        else { cum += g.w;
          if (cum + g.z >= rem) ds = 2;
          else { cum += g.z;
            if (cum + g.y >= rem) ds = 1;
            else { cum += g.y; ds = 0; } } }
        s_digit = 4 * t + ds;
        s_before = before + cum;
      }
    }
    __syncthreads();
    pref = (pref << 8) | (uint32_t)s_digit;
    before = s_before;
  }

  const uint32_t thr = pref;
  const int need = K - before;
  if (t == 0) { gcnt = 0; ecnt = 0; }
  __syncthreads();
#pragma unroll
  for (int j = 0; j < JC; ++j) {
    uint32_t key = k[j];
    if (key > thr) {
      int q = atomicAdd(&gcnt, 1);
      wn[q] = (int)nn[j]; wk[q] = key;
    } else if (key == thr) {
      int q = atomicAdd(&ecnt, 1);
      if (q < K) ebuf[q] = (int)nn[j];
    }
  }
  __syncthreads();
  if (ecnt == need) {
    if (t < need) { wn[before + t] = ebuf[t]; wk[before + t] = thr; }
  } else {
    // rare boundary tie: pick `need` smallest indices among key == thr
    int last = -1;
    for (int r = 0; r < need; ++r) {
      int loc = INT_MAX;
#pragma unroll
      for (int j = 0; j < JC; ++j) {
        int n = (int)nn[j];
        if (k[j] == thr && n > last && n < loc) loc = n;
      }
#pragma unroll
      for (int off = 1; off < 64; off <<= 1) loc = min(loc, __shfl_xor(loc, off));
      if ((t & 63) == 0) rmin4[t >> 6] = loc;
      __syncthreads();
      if (t == 0) {
        int mn = min(min(rmin4[0], rmin4[1]), min(rmin4[2], rmin4[3]));
        wn[before + r] = mn; wk[before + r] = thr; s_last = mn;
      }
      __syncthreads();
      last = s_last;
    }
  }
  __syncthreads();

  // softmax over the K winners (wave 0)
  if (t < 64) {
    float v = (t < K) ? k2f(wk[t]) : -FLT_MAX;
    float mx = v;
#pragma unroll
    for (int off = 1; off < 64; off <<= 1) mx = fmaxf(mx, __shfl_xor(mx, off));
    float e = (t < K) ? expf(v - mx) : 0.f;
    float ss = e;
#pragma unroll
    for (int off = 1; off < 64; off <<= 1) ss += __shfl_xor(ss, off);
    if (t < K) sw[t] = e / ss;
  }
  __syncthreads();

  // fused gather: outT[b][m][c] = sum_j sw[j] * mvT[b][wn[j]][c]  (float4 rows)
  if (t < CV / 4) {
    const float4* tb4 = reinterpret_cast<const float4*>(mvT + (size_t)b * N * CV);
    float4 s4 = make_float4(0.f, 0.f, 0.f, 0.f);
#pragma unroll
    for (int j = 0; j < K; ++j) {
      float wj = sw[j];
      float4 v = tb4[(size_t)wn[j] * (CV / 4) + t];
      s4.x += wj * v.x; s4.y += wj * v.y; s4.z += wj * v.z; s4.w += wj * v.w;
    }
    reinterpret_cast<float4*>(outT + ((size_t)b * M + m) * CV)[t] = s4;
  }
}

}  // namespace

extern "C" void kernel_launch(void* const* d_in, const int* in_sizes, int n_in,
                              void* d_out, int out_size, void* d_ws, size_t ws_size,
                              hipStream_t stream) {
  const float* mk = (const float*)d_in[0];
  const float* qk = (const float*)d_in[1];
  const float* mv = (const float*)d_in[2];
  float* out = (float*)d_out;

  char* w = (char*)d_ws;
  float* asq = (float*)w;
  size_t o = (size_t)B * N * sizeof(float);                 // 103,680 B
  float* mvT = (float*)(w + o);
  o += (size_t)B * N * CV * sizeof(float);                  // +39,813,120 B
  float* outT = (float*)(w + o);
  o += (size_t)B * M * CV * sizeof(float);                  // +4,976,640 B
  uint32_t* cnt = (uint32_t*)(w + o);
  o += (size_t)B * M * NSEG * sizeof(uint32_t);             // +168,480 B
  uint2* pairs = (uint2*)(w + o);
  o += (size_t)B * M * NSEG * CAP * sizeof(uint2);          // +21,565,440 B  (total ~66.6 MB)

  transpose_kernel<<<dim3((N + 63) / 64, CV / 64, B), 256, 0, stream>>>(mv, mvT);
  asq_kernel<<<(B * N + 255) / 256, 256, 0, stream>>>(mk, asq);
  // cnt needs no memset: every (b, m<M, seg) is written by its owning wave.
  fused_kernel<<<dim3(NSEG, (M + 15) / 16, B), 256, 0, stream>>>(mk, qk, asq, cnt, pairs);
  merge_topk_gather<<<dim3(M, B), 256, 0, stream>>>(cnt, pairs, mvT, outT);
  transpose_out_kernel<<<dim3((M + 63) / 64, CV / 64, B), 256, 0, stream>>>(outT, out);
}